// Round 2
// baseline (132.160 us; speedup 1.0000x reference)
//
#include <hip/hip_runtime.h>
#include <hip/hip_bf16.h>

#define N_NODES 100000
#define DEGREE 32
#define N_PAIRS 8192
#define FEAT 9
#define HID 20
#define NOUT 15

// ---------------------------------------------------------------------------
// Kernel 1a: neighbor-mean of features, thread per (node, feat-dim).
// 9 consecutive threads share a node -> contiguous 36B fp32 reads per gather,
// adj index loads broadcast within the group. feat (3.6 MB) is L2/L3-resident.
// ---------------------------------------------------------------------------
__global__ __launch_bounds__(256) void k_neigh_mean(
    const int* __restrict__ adj,
    const float* __restrict__ feat,
    float* __restrict__ s_ws) {
  int t = blockIdx.x * blockDim.x + threadIdx.x;
  if (t >= N_NODES * FEAT) return;
  int node = t / FEAT;
  int j = t - node * FEAT;
  const int* arow = adj + node * DEGREE;
  float s = 0.f;
#pragma unroll
  for (int k = 0; k < DEGREE; ++k) {
    int m = arow[k];
    s += feat[m * FEAT + j];
  }
  s_ws[t] = s * (1.0f / DEGREE);
}

// ---------------------------------------------------------------------------
// Kernel 1b: per-node t[n] = W2 @ relu(W1 @ [feat[n], neigh_mean[n]]).
// Weights staged in LDS (broadcast reads, no conflicts). fp32 accumulate.
// t is stored LINEAR (no relu) because enc2 applies relu only after the mean.
// ---------------------------------------------------------------------------
__global__ __launch_bounds__(256) void k_node_embed(
    const float* __restrict__ feat,
    const float* __restrict__ s_ws,
    const float* __restrict__ W1,   // [HID][2*FEAT]
    const float* __restrict__ W2,   // [NOUT][HID]
    float* __restrict__ t_ws) {
  __shared__ float sW1[HID * 2 * FEAT];
  __shared__ float sW2[NOUT * HID];
  for (int i = threadIdx.x; i < HID * 2 * FEAT; i += blockDim.x)
    sW1[i] = W1[i];
  for (int i = threadIdx.x; i < NOUT * HID; i += blockDim.x)
    sW2[i] = W2[i];
  __syncthreads();

  int n = blockIdx.x * blockDim.x + threadIdx.x;
  if (n >= N_NODES) return;

  float comb[2 * FEAT];
#pragma unroll
  for (int j = 0; j < FEAT; ++j) comb[j] = feat[n * FEAT + j];
#pragma unroll
  for (int j = 0; j < FEAT; ++j) comb[FEAT + j] = s_ws[n * FEAT + j];

  float h1[HID];
#pragma unroll
  for (int i = 0; i < HID; ++i) {
    float acc = 0.f;
#pragma unroll
    for (int j = 0; j < 2 * FEAT; ++j) acc += sW1[i * 2 * FEAT + j] * comb[j];
    h1[i] = fmaxf(acc, 0.f);
  }
#pragma unroll
  for (int d = 0; d < NOUT; ++d) {
    float acc = 0.f;
#pragma unroll
    for (int i = 0; i < HID; ++i) acc += sW2[d * HID + i] * h1[i];
    t_ws[n * NOUT + d] = acc;   // linear (relu comes after the enc2 mean)
  }
}

// ---------------------------------------------------------------------------
// Kernel 2: per (endpoint, out-dim): e = relu(mean over {adj[node], node} of t).
// 15 consecutive threads share an endpoint -> contiguous 60B fp32 gathers.
// Endpoint index == flat to_pred index (pair-major), so e_ws is laid out
// [pair][side][15] == the concat(cat) order for the MLP.
// ---------------------------------------------------------------------------
__global__ __launch_bounds__(256) void k_endpoint(
    const int* __restrict__ to_pred,
    const int* __restrict__ adj,
    const float* __restrict__ t_ws,
    float* __restrict__ e_ws) {
  int t = blockIdx.x * blockDim.x + threadIdx.x;
  if (t >= 2 * N_PAIRS * NOUT) return;
  int ep = t / NOUT;
  int d = t - ep * NOUT;
  int node = to_pred[ep];
  const int* arow = adj + node * DEGREE;
  float s = t_ws[node * NOUT + d];   // self (gcn=True includes self in mean)
#pragma unroll
  for (int k = 0; k < DEGREE; ++k) {
    int m = arow[k];
    s += t_ws[m * NOUT + d];
  }
  e_ws[t] = fmaxf(s * (1.0f / (DEGREE + 1)), 0.f);
}

// ---------------------------------------------------------------------------
// Kernel 3: per-pair 2-layer MLP; weights in LDS. fp32 output.
// ---------------------------------------------------------------------------
__global__ __launch_bounds__(256) void k_mlp(
    const float* __restrict__ e_ws,
    const float* __restrict__ fc1_w,  // [15][30]
    const float* __restrict__ fc1_b,  // [15]
    const float* __restrict__ fc2_w,  // [1][15]
    const float* __restrict__ fc2_b,  // [1]
    float* __restrict__ out) {
  __shared__ float s1[15 * 30];
  __shared__ float b1[15];
  __shared__ float s2[15];
  __shared__ float b2;
  for (int i = threadIdx.x; i < 15 * 30; i += blockDim.x)
    s1[i] = fc1_w[i];
  if (threadIdx.x < 15) {
    b1[threadIdx.x] = fc1_b[threadIdx.x];
    s2[threadIdx.x] = fc2_w[threadIdx.x];
  }
  if (threadIdx.x == 0) b2 = fc2_b[0];
  __syncthreads();

  int p = blockIdx.x * blockDim.x + threadIdx.x;
  if (p >= N_PAIRS) return;

  float cat[30];
#pragma unroll
  for (int j = 0; j < 30; ++j) cat[j] = e_ws[p * 30 + j];

  float acc2 = b2;
#pragma unroll
  for (int i = 0; i < 15; ++i) {
    float acc = b1[i];
#pragma unroll
    for (int j = 0; j < 30; ++j) acc += s1[i * 30 + j] * cat[j];
    acc2 += s2[i] * fmaxf(acc, 0.f);
  }
  out[p] = fmaxf(acc2, 0.f);
}

// ---------------------------------------------------------------------------
extern "C" void kernel_launch(void* const* d_in, const int* in_sizes, int n_in,
                              void* d_out, int out_size, void* d_ws,
                              size_t ws_size, hipStream_t stream) {
  const int* to_pred     = (const int*)d_in[0];
  const int* adj         = (const int*)d_in[1];
  const float* feat      = (const float*)d_in[2];
  const float* W1        = (const float*)d_in[3];
  const float* W2        = (const float*)d_in[4];
  const float* fc1_w     = (const float*)d_in[5];
  const float* fc1_b     = (const float*)d_in[6];
  const float* fc2_w     = (const float*)d_in[7];
  const float* fc2_b     = (const float*)d_in[8];
  float* out             = (float*)d_out;

  char* ws = (char*)d_ws;
  // Workspace layout (all fp32 intermediates, ~10.6 MB total):
  float* t_ws = (float*)ws;                    // 100000*15 fp32 = 6,000,000 B
  float* s_ws = (float*)(ws + 6000000);        // 100000* 9 fp32 = 3,600,000 B
  float* e_ws = (float*)(ws + 9600000);        // 16384*15 fp32  =   983,040 B

  // 1a: neighbor feature mean, 900000 threads
  {
    int total = N_NODES * FEAT;
    k_neigh_mean<<<(total + 255) / 256, 256, 0, stream>>>(adj, feat, s_ws);
  }
  // 1b: per-node embedding t, 100000 threads
  {
    int total = N_NODES;
    k_node_embed<<<(total + 255) / 256, 256, 0, stream>>>(feat, s_ws, W1, W2,
                                                          t_ws);
  }
  // 2: per-endpoint enc2 embedding, 16384*15 threads
  {
    int total = 2 * N_PAIRS * NOUT;
    k_endpoint<<<(total + 255) / 256, 256, 0, stream>>>(to_pred, adj, t_ws,
                                                        e_ws);
  }
  // 3: per-pair MLP, 8192 threads
  {
    int total = N_PAIRS;
    k_mlp<<<(total + 255) / 256, 256, 0, stream>>>(e_ws, fc1_w, fc1_b, fc2_w,
                                                   fc2_b, out);
  }
}

// Round 3
// 119.467 us; speedup vs baseline: 1.1062x; 1.1062x over previous
//
#include <hip/hip_runtime.h>
#include <hip/hip_bf16.h>

#define N_NODES 100000
#define DEGREE 32
#define N_PAIRS 8192
#define FEAT 9
#define HID 20
#define NOUT 15

#define NPB 28   // nodes per block in K1 (28*9 = 252 active lanes of 256)
#define PPB 8    // pairs per block in K2 (8*30 = 240 active lanes of 256)

// ---------------------------------------------------------------------------
// K1: fused enc1-mean + node MLP.
//   phase 1: thread (node, j) gathers 32 neighbor feats (36B contiguous per
//            node across 9 lanes; adj loads broadcast within the 9-lane group)
//            -> comb = [feat[n], mean] staged in LDS.
//   phase 2: (node, i) computes h1[i] = relu(W1[i] . comb)      (LDS)
//   phase 3: (node, d) computes t[n,d] = W2[d] . h1  (linear; relu is applied
//            only after the enc2 mean) -> global t_ws.
// ---------------------------------------------------------------------------
__global__ __launch_bounds__(256) void k_node_all(
    const int* __restrict__ adj,
    const float* __restrict__ feat,
    const float* __restrict__ W1,   // [HID][2*FEAT]
    const float* __restrict__ W2,   // [NOUT][HID]
    float* __restrict__ t_ws) {
  __shared__ float sW1[HID * 2 * FEAT];   // 360
  __shared__ float sW2[NOUT * HID];       // 300
  __shared__ float sComb[NPB][2 * FEAT];  // 28 x 18
  __shared__ float sH[NPB][HID];          // 28 x 20

  int tid = threadIdx.x;
  for (int i = tid; i < HID * 2 * FEAT; i += 256) sW1[i] = W1[i];
  for (int i = tid; i < NOUT * HID; i += 256) sW2[i] = W2[i];

  int base = blockIdx.x * NPB;

  // phase 1: neighbor mean + self feat -> sComb
  if (tid < NPB * FEAT) {
    int nl = tid / FEAT;
    int j = tid - nl * FEAT;
    int n = base + nl;
    if (n < N_NODES) {
      const int* arow = adj + n * DEGREE;
      float s = 0.f;
#pragma unroll
      for (int k = 0; k < DEGREE; ++k) {
        int m = arow[k];
        s += feat[m * FEAT + j];
      }
      sComb[nl][j] = feat[n * FEAT + j];
      sComb[nl][FEAT + j] = s * (1.0f / DEGREE);
    }
  }
  __syncthreads();

  // phase 2: h1 = relu(W1 @ comb), one thread per (node, hid)
  for (int idx = tid; idx < NPB * HID; idx += 256) {
    int nl = idx / HID;
    int i = idx - nl * HID;
    if (base + nl < N_NODES) {
      float acc = 0.f;
#pragma unroll
      for (int j = 0; j < 2 * FEAT; ++j) acc += sW1[i * 2 * FEAT + j] * sComb[nl][j];
      sH[nl][i] = fmaxf(acc, 0.f);
    }
  }
  __syncthreads();

  // phase 3: t = W2 @ h1 (linear), one thread per (node, out)
  for (int idx = tid; idx < NPB * NOUT; idx += 256) {
    int nl = idx / NOUT;
    int d = idx - nl * NOUT;
    int n = base + nl;
    if (n < N_NODES) {
      float acc = 0.f;
#pragma unroll
      for (int i = 0; i < HID; ++i) acc += sW2[d * HID + i] * sH[nl][i];
      t_ws[n * NOUT + d] = acc;
    }
  }
}

// ---------------------------------------------------------------------------
// K2: fused enc2 endpoint aggregation + pair MLP.
//   phase 1: thread (pair, side, d) gathers 33 t-values (60B contiguous per
//            endpoint across 15 lanes) -> e = relu(mean) staged in LDS in
//            concat order [side0 dims | side1 dims].
//   phase 2: (pair, i) computes h[i] = relu(fc1[i] . e + b1[i])   (LDS)
//   phase 3: (pair) computes out = relu(fc2 . h + b2) -> global.
// ---------------------------------------------------------------------------
__global__ __launch_bounds__(256) void k_pair_all(
    const int* __restrict__ to_pred,
    const int* __restrict__ adj,
    const float* __restrict__ t_ws,
    const float* __restrict__ fc1_w,  // [15][30]
    const float* __restrict__ fc1_b,  // [15]
    const float* __restrict__ fc2_w,  // [1][15]
    const float* __restrict__ fc2_b,  // [1]
    float* __restrict__ out) {
  __shared__ float s1[15 * 30];
  __shared__ float b1v[15];
  __shared__ float s2v[15];
  __shared__ float b2v;
  __shared__ float sE[PPB][30];
  __shared__ float sHh[PPB][15];

  int tid = threadIdx.x;
  for (int i = tid; i < 15 * 30; i += 256) s1[i] = fc1_w[i];
  if (tid < 15) {
    b1v[tid] = fc1_b[tid];
    s2v[tid] = fc2_w[tid];
  }
  if (tid == 0) b2v = fc2_b[0];

  int pbase = blockIdx.x * PPB;

  // phase 1: endpoint aggregate (self + 32 neighbors of t, then relu(mean))
  if (tid < PPB * 30) {
    int pl = tid / 30;
    int slot = tid - pl * 30;
    int side = slot / 15;
    int d = slot - side * 15;
    int p = pbase + pl;                 // N_PAIRS % PPB == 0, always in range
    int node = to_pred[2 * p + side];
    const int* arow = adj + node * DEGREE;
    float s = t_ws[node * NOUT + d];    // gcn=True: self included in mean
#pragma unroll
    for (int k = 0; k < DEGREE; ++k) {
      int m = arow[k];
      s += t_ws[m * NOUT + d];
    }
    sE[pl][slot] = fmaxf(s * (1.0f / (DEGREE + 1)), 0.f);
  }
  __syncthreads();

  // phase 2: h = relu(fc1 @ e + b1), one thread per (pair, i)
  if (tid < PPB * 15) {
    int pl = tid / 15;
    int i = tid - pl * 15;
    float acc = b1v[i];
#pragma unroll
    for (int j = 0; j < 30; ++j) acc += s1[i * 30 + j] * sE[pl][j];
    sHh[pl][i] = fmaxf(acc, 0.f);
  }
  __syncthreads();

  // phase 3: out = relu(fc2 @ h + b2), one thread per pair
  if (tid < PPB) {
    float acc = b2v;
#pragma unroll
    for (int i = 0; i < 15; ++i) acc += s2v[i] * sHh[tid][i];
    out[pbase + tid] = fmaxf(acc, 0.f);
  }
}

// ---------------------------------------------------------------------------
extern "C" void kernel_launch(void* const* d_in, const int* in_sizes, int n_in,
                              void* d_out, int out_size, void* d_ws,
                              size_t ws_size, hipStream_t stream) {
  const int* to_pred = (const int*)d_in[0];
  const int* adj     = (const int*)d_in[1];
  const float* feat  = (const float*)d_in[2];
  const float* W1    = (const float*)d_in[3];
  const float* W2    = (const float*)d_in[4];
  const float* fc1_w = (const float*)d_in[5];
  const float* fc1_b = (const float*)d_in[6];
  const float* fc2_w = (const float*)d_in[7];
  const float* fc2_b = (const float*)d_in[8];
  float* out         = (float*)d_out;

  float* t_ws = (float*)d_ws;  // 100000*15 fp32 = 6 MB

  int grid1 = (N_NODES + NPB - 1) / NPB;   // 3572
  k_node_all<<<grid1, 256, 0, stream>>>(adj, feat, W1, W2, t_ws);

  int grid2 = N_PAIRS / PPB;               // 1024
  k_pair_all<<<grid2, 256, 0, stream>>>(to_pred, adj, t_ws, fc1_w, fc1_b,
                                        fc2_w, fc2_b, out);
}